// Round 4
// baseline (923.890 us; speedup 1.0000x reference)
//
#include <hip/hip_runtime.h>
#include <math.h>

#define NTOK   4096
#define NFEAT  512
#define NDIM   64
#define RROWS  8
#define NBANDS 512   // bands of 8 consecutive rows per batch

// ---------------- QK projection + RoPE + initial charge ----------------
__global__ __launch_bounds__(256) void qk_kernel(
    const float* __restrict__ feat, const float* __restrict__ cosb,
    const float* __restrict__ sinb, const float* __restrict__ Wq,
    const float* __restrict__ Wk, const float* __restrict__ cw,
    const float* __restrict__ cbp, float* __restrict__ Q, float* __restrict__ K,
    float* __restrict__ cur)
{
  __shared__ __align__(16) float smem[RROWS * NFEAT];  // 16 KB
  const int tid  = threadIdx.x;
  const int row0 = blockIdx.x * RROWS;

  const float4* fb4 = (const float4*)(feat + (size_t)row0 * NFEAT);
  float4* sm4 = (float4*)smem;
#pragma unroll
  for (int i = tid; i < RROWS * NFEAT / 4; i += 256) sm4[i] = fb4[i];
  __syncthreads();

  const int r   = tid >> 5;
  const int c   = tid & 31;
  const int isQ = (c < 16);
  const int d0  = (c & 15) * 4;
  const float* __restrict__ Wp = isQ ? Wq : Wk;
  const float* fr = smem + (r << 9);

  float a0 = 0.f, a1 = 0.f, a2 = 0.f, a3 = 0.f;
  for (int k = 0; k < NFEAT; ++k) {
    float fv = fr[k];
    float4 w = *(const float4*)(Wp + k * NDIM + d0);
    a0 = fmaf(fv, w.x, a0); a1 = fmaf(fv, w.y, a1);
    a2 = fmaf(fv, w.z, a2); a3 = fmaf(fv, w.w, a3);
  }

  float accc = 0.f;
#pragma unroll
  for (int j = 0; j < 16; ++j) accc = fmaf(fr[c + (j << 5)], cw[c + (j << 5)], accc);
#pragma unroll
  for (int o = 16; o > 0; o >>= 1) accc += __shfl_down(accc, o, 64);
  if (c == 0) {
    float cb = cbp[0];
    cur[row0 + r] = 1.f / (1.f + __expf(-(accc + cb)));
  }
  __syncthreads();

  float* sraw = smem;
  {
    float* dst = sraw + r * 132 + (isQ ? 0 : 64) + d0;
    dst[0] = a0; dst[1] = a1; dst[2] = a2; dst[3] = a3;
  }
  __syncthreads();

#pragma unroll
  for (int i = tid; i < RROWS * NDIM; i += 256) {
    int rr = i >> 6, d = i & 63;
    int g = row0 + rr, n = g & (NTOK - 1);
    float cv = cosb[(n << 6) + d], sv = sinb[(n << 6) + d];
    float qv = sraw[rr * 132 + d];
    float qr = (d < 32) ? -sraw[rr * 132 + d + 32] : sraw[rr * 132 + d - 32];
    Q[(size_t)g * NDIM + d] = qv * cv + qr * sv;
    float kv = sraw[rr * 132 + 64 + d];
    float kr = (d < 32) ? -sraw[rr * 132 + 64 + d + 32] : sraw[rr * 132 + 64 + d - 32];
    K[(size_t)g * NDIM + d] = kv * cv + kr * sv;
  }
}

// ---------------- compat = Q K^T / sqrt(64), lower-triangular 128x128 tiles ----------------
__global__ __launch_bounds__(256) void compat_kernel(
    const float* __restrict__ Q, const float* __restrict__ K, float* __restrict__ C)
{
  __shared__ __align__(16) float Qs[32][132];
  __shared__ __align__(16) float Ks[32][132];
  int p = blockIdx.x, b = 0;
  if (p >= 528) { b = 1; p -= 528; }
  int ti = (int)((sqrtf(8.f * p + 1.f) - 1.f) * 0.5f);
  while ((ti + 1) * (ti + 2) / 2 <= p) ++ti;
  while (ti * (ti + 1) / 2 > p) --ti;
  int tj = p - ti * (ti + 1) / 2;

  const int tid = threadIdx.x;
  const int ty = tid >> 4, tx = tid & 15;
  const int i0 = ty * 8, j0 = tx * 8;
  const size_t qbase = ((size_t)b * NTOK + (size_t)ti * 128) * NDIM;
  const size_t kbase = ((size_t)b * NTOK + (size_t)tj * 128) * NDIM;

  float acc[8][8];
#pragma unroll
  for (int ii = 0; ii < 8; ++ii)
#pragma unroll
    for (int jj = 0; jj < 8; ++jj) acc[ii][jj] = 0.f;

  for (int dk = 0; dk < NDIM; dk += 32) {
    __syncthreads();
    for (int i = tid; i < 128 * 32; i += 256) {
      int row = i >> 5, d = i & 31;
      Qs[d][row] = Q[qbase + (size_t)row * NDIM + dk + d];
      Ks[d][row] = K[kbase + (size_t)row * NDIM + dk + d];
    }
    __syncthreads();
#pragma unroll
    for (int d = 0; d < 32; ++d) {
      float4 q0 = *(const float4*)&Qs[d][i0];
      float4 q1 = *(const float4*)&Qs[d][i0 + 4];
      float4 k0 = *(const float4*)&Ks[d][j0];
      float4 k1 = *(const float4*)&Ks[d][j0 + 4];
      float av[8] = {q0.x, q0.y, q0.z, q0.w, q1.x, q1.y, q1.z, q1.w};
      float bv[8] = {k0.x, k0.y, k0.z, k0.w, k1.x, k1.y, k1.z, k1.w};
#pragma unroll
      for (int ii = 0; ii < 8; ++ii)
#pragma unroll
        for (int jj = 0; jj < 8; ++jj)
          acc[ii][jj] = fmaf(av[ii], bv[jj], acc[ii][jj]);
    }
  }
#pragma unroll
  for (int ii = 0; ii < 8; ++ii) {
    size_t grow = (size_t)b * NTOK + (size_t)ti * 128 + i0 + ii;
    float4 w0 = make_float4(acc[ii][0] * 0.125f, acc[ii][1] * 0.125f,
                            acc[ii][2] * 0.125f, acc[ii][3] * 0.125f);
    float4 w1 = make_float4(acc[ii][4] * 0.125f, acc[ii][5] * 0.125f,
                            acc[ii][6] * 0.125f, acc[ii][7] * 0.125f);
    *(float4*)&C[grow * NTOK + (size_t)tj * 128 + j0]     = w0;
    *(float4*)&C[grow * NTOK + (size_t)tj * 128 + j0 + 4] = w1;
  }
}

// ---------------- softmax sweep: one FULL row per wave, branch-free load block ----------------
// logits_t[n,m] = compat[n,m] * (1 + ss * sum_{c<NC} chistT[c][n]*chistT[c][m])
// All NSC compat loads for the row issue in ONE basic block (sched_barrier pins them)
// -> 8-16 KB in flight per wave, a single waitcnt cascade per row, no control-flow
// between loads. Masking is per-element cndmask to -inf, never a branch.
template <int MODE, int NSC, int NC>
__device__ __forceinline__ void row_body(
    const int b, const int n, const int l,
    const float* __restrict__ compat, const float* __restrict__ chT,
    const float ss, float* __restrict__ rp, float* __restrict__ out)
{
  const int scmax = n >> 8;
  const float4* __restrict__ rowv =
      (const float4*)(compat + ((size_t)((b << 12) + n) << 12));

  float4 cv[NSC];
#pragma unroll
  for (int sc = 0; sc < NSC; ++sc) cv[sc] = rowv[(sc << 6) + l];
  __builtin_amdgcn_sched_barrier(0);   // keep all row loads issued before compute

  float h[NC > 0 ? NC : 1];
#pragma unroll
  for (int c = 0; c < NC; ++c) h[c] = ss * chT[(c << 13) + n];

  float vmax = -INFINITY;
#pragma unroll
  for (int sc = 0; sc < NSC; ++sc) {
    const int base = (sc << 8) + (l << 2);
    float dx = 0.f, dy = 0.f, dz = 0.f, dw = 0.f;
#pragma unroll
    for (int c = 0; c < NC; ++c) {
      float4 g = *(const float4*)(chT + (c << 13) + base);
      dx = fmaf(g.x, h[c], dx);
      dy = fmaf(g.y, h[c], dy);
      dz = fmaf(g.z, h[c], dz);
      dw = fmaf(g.w, h[c], dw);
    }
    float4 q = cv[sc], x;
    x.x = fmaf(q.x, dx, q.x);
    x.y = fmaf(q.y, dy, q.y);
    x.z = fmaf(q.z, dz, q.z);
    x.w = fmaf(q.w, dw, q.w);
    x.x = (base + 0 <= n) ? x.x : -INFINITY;
    x.y = (base + 1 <= n) ? x.y : -INFINITY;
    x.z = (base + 2 <= n) ? x.z : -INFINITY;
    x.w = (base + 3 <= n) ? x.w : -INFINITY;
    cv[sc] = x;
    vmax = fmaxf(vmax, fmaxf(fmaxf(x.x, x.y), fmaxf(x.z, x.w)));
  }
#pragma unroll
  for (int o = 32; o > 0; o >>= 1) vmax = fmaxf(vmax, __shfl_xor(vmax, o, 64));

  float ssum = 0.f;
#pragma unroll
  for (int sc = 0; sc < NSC; ++sc) {
    float4 v;
    v.x = __expf(cv[sc].x - vmax);   // exp(-inf - M) = 0 for masked cols
    v.y = __expf(cv[sc].y - vmax);
    v.z = __expf(cv[sc].z - vmax);
    v.w = __expf(cv[sc].w - vmax);
    cv[sc] = v;
    ssum += (v.x + v.y) + (v.z + v.w);
  }
#pragma unroll
  for (int o = 32; o > 0; o >>= 1) ssum += __shfl_xor(ssum, o, 64);
  const float inv = 1.f / ssum;

  if (MODE == 0) {
    // permuted slots: slot sc*256+i*64+l <-> col sc*256+4l+i ; 2 lanes/bank = free
#pragma unroll
    for (int sc = 0; sc < NSC; ++sc) {
      if (sc > scmax) continue;        // wave-uniform scalar skip (post-load, harmless)
      const int slot = (sc << 8) + l;
      atomicAdd(&rp[slot      ], cv[sc].x * inv);
      atomicAdd(&rp[slot +  64], cv[sc].y * inv);
      atomicAdd(&rp[slot + 128], cv[sc].z * inv);
      atomicAdd(&rp[slot + 192], cv[sc].w * inv);
    }
  } else {
    float4* __restrict__ orow = (float4*)(out + ((size_t)((b << 12) + n) << 12));
#pragma unroll
    for (int sc = 0; sc < NSC; ++sc) {
      if (sc > scmax) continue;        // cols beyond (n|127) are memset-0 already
      float4 v = cv[sc];
      v.x *= inv; v.y *= inv; v.z *= inv; v.w *= inv;
      orow[(sc << 6) + l] = v;         // masked cols carry exp(-inf)=0
    }
  }
}

// grid 1024 blocks (2 batches * 512 bands), 512 threads = 8 waves, one row per wave.
// Bands reversed so long-tier bands (rows >= 2048, NSC=16) dispatch first.
template <int MODE, int NC>
__global__ __launch_bounds__(512) void pass_kernel(
    const float* __restrict__ compat, const float* __restrict__ chistT,
    const float* __restrict__ ssp, float* __restrict__ partial,
    float* __restrict__ out)
{
  __shared__ float rp[NTOK];           // 16 KB permuted column partials (MODE 0)
  const int tid = threadIdx.x;
  const int b    = blockIdx.x >> 9;
  const int band = (NBANDS - 1) - (blockIdx.x & (NBANDS - 1));
  const int w = __builtin_amdgcn_readfirstlane(tid >> 6);  // wave id -> SGPR
  const int l = tid & 63;
  const int n = (band << 3) + w;
  const float ss = ssp[0];
  const float* __restrict__ chT = chistT + (b << 12);  // comp c at +(c<<13)

  if (MODE == 0) {
    for (int i = tid; i < NTOK; i += 512) rp[i] = 0.f;
    __syncthreads();
  }

  if (band >= 256)
    row_body<MODE, 16, NC>(b, n, l, compat, chT, ss, rp, out);
  else
    row_body<MODE, 8, NC>(b, n, l, compat, chT, ss, rp, out);

  if (MODE == 0) {
    __syncthreads();
    float4* __restrict__ pp4 =
        (float4*)(partial + ((size_t)b * NBANDS + band) * (size_t)NTOK);
    const float4* rp4 = (const float4*)rp;
    for (int i = tid; i < NTOK / 4; i += 512) pp4[i] = rp4[i];
  }
}

// ---------------- fold partials -> received, update charge ----------------
// Band g covers rows 8g..8g+7 -> touches col m iff 8g+7 >= m <=> g >= m>>3.
// Threads iterate PERMUTED slots (coalesced); logical col recovered for final writes.
__global__ __launch_bounds__(256) void reduce_update_kernel(
    const float* __restrict__ partial, const float* __restrict__ cdp,
    float* __restrict__ cur, float* __restrict__ chistT, int step)
{
  __shared__ float s[8][32];
  const int tid = threadIdx.x;
  const int b = blockIdx.x >> 7;
  const int s0 = (blockIdx.x & 127) << 5;
  const int ml = tid & 31, seg = tid >> 5;
  const int slot = s0 + ml;
  const int m = (slot & ~255) | ((slot & 63) << 2) | ((slot >> 6) & 3);  // inverse perm
  const int bmin = m >> 3;
  float sum = 0.f;
  const float* pb = partial + (size_t)b * NBANDS * NTOK + slot;
  for (int band = bmin + seg; band < NBANDS; band += 8)
    sum += pb[(size_t)band << 12];
  s[seg][ml] = sum;
  __syncthreads();
  if (seg == 0) {
    float r = s[0][ml] + s[1][ml] + s[2][ml] + s[3][ml] +
              s[4][ml] + s[5][ml] + s[6][ml] + s[7][ml];
    float sg = 1.f / (1.f + __expf(-(r - 1.f)));
    float cd = cdp[0];
    int idx = (b << 12) + m;
    float c = cur[idx] * (1.f - cd * sg);
    cur[idx] = c;
    chistT[(step << 13) + idx] = c;
  }
}

extern "C" void kernel_launch(void* const* d_in, const int* in_sizes, int n_in,
                              void* d_out, int out_size, void* d_ws, size_t ws_size,
                              hipStream_t stream) {
  const float* feat = (const float*)d_in[0];
  const float* cosb = (const float*)d_in[1];
  const float* sinb = (const float*)d_in[2];
  // d_in[3] = mask: deterministic tril, handled structurally
  const float* Wq  = (const float*)d_in[4];
  const float* Wk  = (const float*)d_in[5];
  const float* cw  = (const float*)d_in[6];
  const float* cbp = (const float*)d_in[7];
  const float* ssp = (const float*)d_in[8];
  const float* cdp = (const float*)d_in[9];
  float* out = (float*)d_out;

  float* ws      = (float*)d_ws;
  float* Q       = ws;                 // 2*4096*64
  float* K       = ws + 524288;        // 2*4096*64
  float* chistT  = ws + 1048576;       // 4 steps * 2*4096  (transposed charge history)
  float* cur     = ws + 1081344;       // 2*4096
  float* partial = ws + 1089536;       // 2*512*4096 (permuted column slots)

  // compat lives in d_out (134 MB); final pass overwrites it in place.
  qk_kernel<<<1024, 256, 0, stream>>>(feat, cosb, sinb, Wq, Wk, cw, cbp, Q, K, cur);
  compat_kernel<<<1056, 256, 0, stream>>>(Q, K, out);

  pass_kernel<0, 0><<<1024, 512, 0, stream>>>(out, chistT, ssp, partial, nullptr);
  reduce_update_kernel<<<256, 256, 0, stream>>>(partial, cdp, cur, chistT, 0);
  pass_kernel<0, 1><<<1024, 512, 0, stream>>>(out, chistT, ssp, partial, nullptr);
  reduce_update_kernel<<<256, 256, 0, stream>>>(partial, cdp, cur, chistT, 1);
  pass_kernel<0, 2><<<1024, 512, 0, stream>>>(out, chistT, ssp, partial, nullptr);
  reduce_update_kernel<<<256, 256, 0, stream>>>(partial, cdp, cur, chistT, 2);
  pass_kernel<0, 3><<<1024, 512, 0, stream>>>(out, chistT, ssp, partial, nullptr);
  reduce_update_kernel<<<256, 256, 0, stream>>>(partial, cdp, cur, chistT, 3);
  pass_kernel<1, 4><<<1024, 512, 0, stream>>>(out, chistT, ssp, nullptr, out);
}

// Round 6
// 901.578 us; speedup vs baseline: 1.0247x; 1.0247x over previous
//
#include <hip/hip_runtime.h>
#include <math.h>

#define NTOK   4096
#define NFEAT  512
#define NDIM   64
#define RROWS  8
#define NBANDS 512   // bands of 8 consecutive rows per batch

typedef float v4f __attribute__((ext_vector_type(4)));

// ---------------- QK projection + RoPE + initial charge ----------------
__global__ __launch_bounds__(256) void qk_kernel(
    const float* __restrict__ feat, const float* __restrict__ cosb,
    const float* __restrict__ sinb, const float* __restrict__ Wq,
    const float* __restrict__ Wk, const float* __restrict__ cw,
    const float* __restrict__ cbp, float* __restrict__ Q, float* __restrict__ K,
    float* __restrict__ cur)
{
  __shared__ __align__(16) float smem[RROWS * NFEAT];  // 16 KB
  const int tid  = threadIdx.x;
  const int row0 = blockIdx.x * RROWS;

  const float4* fb4 = (const float4*)(feat + (size_t)row0 * NFEAT);
  float4* sm4 = (float4*)smem;
#pragma unroll
  for (int i = tid; i < RROWS * NFEAT / 4; i += 256) sm4[i] = fb4[i];
  __syncthreads();

  const int r   = tid >> 5;
  const int c   = tid & 31;
  const int isQ = (c < 16);
  const int d0  = (c & 15) * 4;
  const float* __restrict__ Wp = isQ ? Wq : Wk;
  const float* fr = smem + (r << 9);

  float a0 = 0.f, a1 = 0.f, a2 = 0.f, a3 = 0.f;
  for (int k = 0; k < NFEAT; ++k) {
    float fv = fr[k];
    float4 w = *(const float4*)(Wp + k * NDIM + d0);
    a0 = fmaf(fv, w.x, a0); a1 = fmaf(fv, w.y, a1);
    a2 = fmaf(fv, w.z, a2); a3 = fmaf(fv, w.w, a3);
  }

  float accc = 0.f;
#pragma unroll
  for (int j = 0; j < 16; ++j) accc = fmaf(fr[c + (j << 5)], cw[c + (j << 5)], accc);
#pragma unroll
  for (int o = 16; o > 0; o >>= 1) accc += __shfl_down(accc, o, 64);
  if (c == 0) {
    float cb = cbp[0];
    cur[row0 + r] = 1.f / (1.f + __expf(-(accc + cb)));
  }
  __syncthreads();

  float* sraw = smem;
  {
    float* dst = sraw + r * 132 + (isQ ? 0 : 64) + d0;
    dst[0] = a0; dst[1] = a1; dst[2] = a2; dst[3] = a3;
  }
  __syncthreads();

#pragma unroll
  for (int i = tid; i < RROWS * NDIM; i += 256) {
    int rr = i >> 6, d = i & 63;
    int g = row0 + rr, n = g & (NTOK - 1);
    float cv = cosb[(n << 6) + d], sv = sinb[(n << 6) + d];
    float qv = sraw[rr * 132 + d];
    float qr = (d < 32) ? -sraw[rr * 132 + d + 32] : sraw[rr * 132 + d - 32];
    Q[(size_t)g * NDIM + d] = qv * cv + qr * sv;
    float kv = sraw[rr * 132 + 64 + d];
    float kr = (d < 32) ? -sraw[rr * 132 + 64 + d + 32] : sraw[rr * 132 + 64 + d - 32];
    K[(size_t)g * NDIM + d] = kv * cv + kr * sv;
  }
}

// ---------------- compat = Q K^T / sqrt(64), lower-triangular 128x128 tiles ----------------
__global__ __launch_bounds__(256) void compat_kernel(
    const float* __restrict__ Q, const float* __restrict__ K, float* __restrict__ C)
{
  __shared__ __align__(16) float Qs[32][132];
  __shared__ __align__(16) float Ks[32][132];
  int p = blockIdx.x, b = 0;
  if (p >= 528) { b = 1; p -= 528; }
  int ti = (int)((sqrtf(8.f * p + 1.f) - 1.f) * 0.5f);
  while ((ti + 1) * (ti + 2) / 2 <= p) ++ti;
  while (ti * (ti + 1) / 2 > p) --ti;
  int tj = p - ti * (ti + 1) / 2;

  const int tid = threadIdx.x;
  const int ty = tid >> 4, tx = tid & 15;
  const int i0 = ty * 8, j0 = tx * 8;
  const size_t qbase = ((size_t)b * NTOK + (size_t)ti * 128) * NDIM;
  const size_t kbase = ((size_t)b * NTOK + (size_t)tj * 128) * NDIM;

  float acc[8][8];
#pragma unroll
  for (int ii = 0; ii < 8; ++ii)
#pragma unroll
    for (int jj = 0; jj < 8; ++jj) acc[ii][jj] = 0.f;

  for (int dk = 0; dk < NDIM; dk += 32) {
    __syncthreads();
    for (int i = tid; i < 128 * 32; i += 256) {
      int row = i >> 5, d = i & 31;
      Qs[d][row] = Q[qbase + (size_t)row * NDIM + dk + d];
      Ks[d][row] = K[kbase + (size_t)row * NDIM + dk + d];
    }
    __syncthreads();
#pragma unroll
    for (int d = 0; d < 32; ++d) {
      float4 q0 = *(const float4*)&Qs[d][i0];
      float4 q1 = *(const float4*)&Qs[d][i0 + 4];
      float4 k0 = *(const float4*)&Ks[d][j0];
      float4 k1 = *(const float4*)&Ks[d][j0 + 4];
      float av[8] = {q0.x, q0.y, q0.z, q0.w, q1.x, q1.y, q1.z, q1.w};
      float bv[8] = {k0.x, k0.y, k0.z, k0.w, k1.x, k1.y, k1.z, k1.w};
#pragma unroll
      for (int ii = 0; ii < 8; ++ii)
#pragma unroll
        for (int jj = 0; jj < 8; ++jj)
          acc[ii][jj] = fmaf(av[ii], bv[jj], acc[ii][jj]);
    }
  }
#pragma unroll
  for (int ii = 0; ii < 8; ++ii) {
    size_t grow = (size_t)b * NTOK + (size_t)ti * 128 + i0 + ii;
    float4 w0 = make_float4(acc[ii][0] * 0.125f, acc[ii][1] * 0.125f,
                            acc[ii][2] * 0.125f, acc[ii][3] * 0.125f);
    float4 w1 = make_float4(acc[ii][4] * 0.125f, acc[ii][5] * 0.125f,
                            acc[ii][6] * 0.125f, acc[ii][7] * 0.125f);
    *(float4*)&C[grow * NTOK + (size_t)tj * 128 + j0]     = w0;
    *(float4*)&C[grow * NTOK + (size_t)tj * 128 + j0 + 4] = w1;
  }
}

// ---------------- softmax sweep: one row per wave, ONE-asm batched load+drain ----------------
// The entire row's loads AND the vmcnt(0) drain live inside a single asm blob with
// early-clobber outputs: when the asm retires, every output register genuinely holds
// its data. No issue-to-drain window exists for the compiler to corrupt (round-5 bug).
// 4 base pointers because the offset immediate caps at 4095 B (4 supercols each).
template <int MODE, int NSC, int NC>
__device__ __forceinline__ void row_body(
    const int b, const int n, const int l,
    const float* __restrict__ compat, const float* __restrict__ chT,
    const float ss, float* __restrict__ rp, float* __restrict__ out)
{
  const int scmax = n >> 8;
  const float* __restrict__ rowf = compat + ((size_t)((b << 12) + n) << 12);
  const float* base = rowf + (l << 2);

  v4f cv[NSC];
  if constexpr (NSC == 16) {
    asm volatile(
      "global_load_dwordx4 %0, %16, off\n\t"
      "global_load_dwordx4 %1, %16, off offset:1024\n\t"
      "global_load_dwordx4 %2, %16, off offset:2048\n\t"
      "global_load_dwordx4 %3, %16, off offset:3072\n\t"
      "global_load_dwordx4 %4, %17, off\n\t"
      "global_load_dwordx4 %5, %17, off offset:1024\n\t"
      "global_load_dwordx4 %6, %17, off offset:2048\n\t"
      "global_load_dwordx4 %7, %17, off offset:3072\n\t"
      "global_load_dwordx4 %8, %18, off\n\t"
      "global_load_dwordx4 %9, %18, off offset:1024\n\t"
      "global_load_dwordx4 %10, %18, off offset:2048\n\t"
      "global_load_dwordx4 %11, %18, off offset:3072\n\t"
      "global_load_dwordx4 %12, %19, off\n\t"
      "global_load_dwordx4 %13, %19, off offset:1024\n\t"
      "global_load_dwordx4 %14, %19, off offset:2048\n\t"
      "global_load_dwordx4 %15, %19, off offset:3072\n\t"
      "s_waitcnt vmcnt(0)"
      : "=&v"(cv[0]),  "=&v"(cv[1]),  "=&v"(cv[2]),  "=&v"(cv[3]),
        "=&v"(cv[4]),  "=&v"(cv[5]),  "=&v"(cv[6]),  "=&v"(cv[7]),
        "=&v"(cv[8]),  "=&v"(cv[9]),  "=&v"(cv[10]), "=&v"(cv[11]),
        "=&v"(cv[12]), "=&v"(cv[13]), "=&v"(cv[14]), "=&v"(cv[15])
      : "v"(base), "v"(base + 1024), "v"(base + 2048), "v"(base + 3072)
      : "memory");
  } else {
    asm volatile(
      "global_load_dwordx4 %0, %8, off\n\t"
      "global_load_dwordx4 %1, %8, off offset:1024\n\t"
      "global_load_dwordx4 %2, %8, off offset:2048\n\t"
      "global_load_dwordx4 %3, %8, off offset:3072\n\t"
      "global_load_dwordx4 %4, %9, off\n\t"
      "global_load_dwordx4 %5, %9, off offset:1024\n\t"
      "global_load_dwordx4 %6, %9, off offset:2048\n\t"
      "global_load_dwordx4 %7, %9, off offset:3072\n\t"
      "s_waitcnt vmcnt(0)"
      : "=&v"(cv[0]), "=&v"(cv[1]), "=&v"(cv[2]), "=&v"(cv[3]),
        "=&v"(cv[4]), "=&v"(cv[5]), "=&v"(cv[6]), "=&v"(cv[7])
      : "v"(base), "v"(base + 1024)
      : "memory");
  }

  float h[NC > 0 ? NC : 1];
#pragma unroll
  for (int c = 0; c < NC; ++c) h[c] = ss * chT[(c << 13) + n];

  float vmax = -INFINITY;
#pragma unroll
  for (int sc = 0; sc < NSC; ++sc) {
    const int base_c = (sc << 8) + (l << 2);
    float dx = 0.f, dy = 0.f, dz = 0.f, dw = 0.f;
#pragma unroll
    for (int c = 0; c < NC; ++c) {
      float4 g = *(const float4*)(chT + (c << 13) + base_c);
      dx = fmaf(g.x, h[c], dx);
      dy = fmaf(g.y, h[c], dy);
      dz = fmaf(g.z, h[c], dz);
      dw = fmaf(g.w, h[c], dw);
    }
    float x0 = fmaf(cv[sc].x, dx, cv[sc].x);
    float x1 = fmaf(cv[sc].y, dy, cv[sc].y);
    float x2 = fmaf(cv[sc].z, dz, cv[sc].z);
    float x3 = fmaf(cv[sc].w, dw, cv[sc].w);
    x0 = (base_c + 0 <= n) ? x0 : -INFINITY;   // per-element mask, never a branch
    x1 = (base_c + 1 <= n) ? x1 : -INFINITY;
    x2 = (base_c + 2 <= n) ? x2 : -INFINITY;
    x3 = (base_c + 3 <= n) ? x3 : -INFINITY;
    cv[sc].x = x0; cv[sc].y = x1; cv[sc].z = x2; cv[sc].w = x3;
    vmax = fmaxf(vmax, fmaxf(fmaxf(x0, x1), fmaxf(x2, x3)));
  }
#pragma unroll
  for (int o = 32; o > 0; o >>= 1) vmax = fmaxf(vmax, __shfl_xor(vmax, o, 64));

  float ssum = 0.f;
#pragma unroll
  for (int sc = 0; sc < NSC; ++sc) {
    float v0 = __expf(cv[sc].x - vmax);        // exp(-inf - M) = 0 for masked cols
    float v1 = __expf(cv[sc].y - vmax);
    float v2 = __expf(cv[sc].z - vmax);
    float v3 = __expf(cv[sc].w - vmax);
    cv[sc].x = v0; cv[sc].y = v1; cv[sc].z = v2; cv[sc].w = v3;
    ssum += (v0 + v1) + (v2 + v3);
  }
#pragma unroll
  for (int o = 32; o > 0; o >>= 1) ssum += __shfl_xor(ssum, o, 64);
  const float inv = 1.f / ssum;

  if (MODE == 0) {
    // permuted slots: slot sc*256+i*64+l <-> col sc*256+4l+i ; 2 lanes/bank = free
#pragma unroll
    for (int sc = 0; sc < NSC; ++sc) {
      if (sc > scmax) continue;                // wave-uniform skip (post-drain, harmless)
      const int slot = (sc << 8) + l;
      atomicAdd(&rp[slot      ], cv[sc].x * inv);
      atomicAdd(&rp[slot +  64], cv[sc].y * inv);
      atomicAdd(&rp[slot + 128], cv[sc].z * inv);
      atomicAdd(&rp[slot + 192], cv[sc].w * inv);
    }
  } else {
    float4* __restrict__ orow = (float4*)(out + ((size_t)((b << 12) + n) << 12));
#pragma unroll
    for (int sc = 0; sc < NSC; ++sc) {
      if (sc > scmax) continue;                // cols beyond (n|255) are memset-0 already
      float4 v;
      v.x = cv[sc].x * inv; v.y = cv[sc].y * inv;
      v.z = cv[sc].z * inv; v.w = cv[sc].w * inv;
      orow[(sc << 6) + l] = v;                 // masked cols carry exp(-inf)=0
    }
  }
}

// grid 1024 blocks (2 batches * 512 bands), 512 threads = 8 waves, one row per wave.
// Bands reversed so long-tier bands (rows >= 2048, NSC=16) dispatch first.
template <int MODE, int NC>
__global__ __launch_bounds__(512) void pass_kernel(
    const float* __restrict__ compat, const float* __restrict__ chistT,
    const float* __restrict__ ssp, float* __restrict__ partial,
    float* __restrict__ out)
{
  __shared__ float rp[NTOK];           // 16 KB permuted column partials (MODE 0)
  const int tid = threadIdx.x;
  const int b    = blockIdx.x >> 9;
  const int band = (NBANDS - 1) - (blockIdx.x & (NBANDS - 1));
  const int w = __builtin_amdgcn_readfirstlane(tid >> 6);  // wave id -> SGPR
  const int l = tid & 63;
  const int n = (band << 3) + w;
  const float ss = ssp[0];
  const float* __restrict__ chT = chistT + (b << 12);  // comp c at +(c<<13)

  if (MODE == 0) {                     // zero + sync BEFORE the load window
    for (int i = tid; i < NTOK; i += 512) rp[i] = 0.f;
    __syncthreads();
  }

  if (band >= 256)
    row_body<MODE, 16, NC>(b, n, l, compat, chT, ss, rp, out);
  else
    row_body<MODE, 8, NC>(b, n, l, compat, chT, ss, rp, out);

  if (MODE == 0) {
    __syncthreads();
    float4* __restrict__ pp4 =
        (float4*)(partial + ((size_t)b * NBANDS + band) * (size_t)NTOK);
    const float4* rp4 = (const float4*)rp;
    for (int i = tid; i < NTOK / 4; i += 512) pp4[i] = rp4[i];
  }
}

// ---------------- fold partials -> received, update charge (round-4 proven) ----------------
// Band g covers rows 8g..8g+7 -> touches col m iff g >= m>>3.
__global__ __launch_bounds__(256) void reduce_update_kernel(
    const float* __restrict__ partial, const float* __restrict__ cdp,
    float* __restrict__ cur, float* __restrict__ chistT, int step)
{
  __shared__ float s[8][32];
  const int tid = threadIdx.x;
  const int b = blockIdx.x >> 7;
  const int s0 = (blockIdx.x & 127) << 5;
  const int ml = tid & 31, seg = tid >> 5;
  const int slot = s0 + ml;
  const int m = (slot & ~255) | ((slot & 63) << 2) | ((slot >> 6) & 3);  // inverse perm
  const int bmin = m >> 3;
  float sum = 0.f;
  const float* pb = partial + (size_t)b * NBANDS * NTOK + slot;
  for (int band = bmin + seg; band < NBANDS; band += 8)
    sum += pb[(size_t)band << 12];
  s[seg][ml] = sum;
  __syncthreads();
  if (seg == 0) {
    float r = s[0][ml] + s[1][ml] + s[2][ml] + s[3][ml] +
              s[4][ml] + s[5][ml] + s[6][ml] + s[7][ml];
    float sg = 1.f / (1.f + __expf(-(r - 1.f)));
    float cd = cdp[0];
    int idx = (b << 12) + m;
    float c = cur[idx] * (1.f - cd * sg);
    cur[idx] = c;
    chistT[(step << 13) + idx] = c;
  }
}

extern "C" void kernel_launch(void* const* d_in, const int* in_sizes, int n_in,
                              void* d_out, int out_size, void* d_ws, size_t ws_size,
                              hipStream_t stream) {
  const float* feat = (const float*)d_in[0];
  const float* cosb = (const float*)d_in[1];
  const float* sinb = (const float*)d_in[2];
  // d_in[3] = mask: deterministic tril, handled structurally
  const float* Wq  = (const float*)d_in[4];
  const float* Wk  = (const float*)d_in[5];
  const float* cw  = (const float*)d_in[6];
  const float* cbp = (const float*)d_in[7];
  const float* ssp = (const float*)d_in[8];
  const float* cdp = (const float*)d_in[9];
  float* out = (float*)d_out;

  float* ws      = (float*)d_ws;
  float* Q       = ws;                 // 2*4096*64
  float* K       = ws + 524288;        // 2*4096*64
  float* chistT  = ws + 1048576;       // 4 steps * 2*4096  (transposed charge history)
  float* cur     = ws + 1081344;       // 2*4096
  float* partial = ws + 1089536;       // 2*512*4096 (permuted column slots)

  // compat lives in d_out (134 MB); final pass overwrites it in place.
  qk_kernel<<<1024, 256, 0, stream>>>(feat, cosb, sinb, Wq, Wk, cw, cbp, Q, K, cur);
  compat_kernel<<<1056, 256, 0, stream>>>(Q, K, out);

  pass_kernel<0, 0><<<1024, 512, 0, stream>>>(out, chistT, ssp, partial, nullptr);
  reduce_update_kernel<<<256, 256, 0, stream>>>(partial, cdp, cur, chistT, 0);
  pass_kernel<0, 1><<<1024, 512, 0, stream>>>(out, chistT, ssp, partial, nullptr);
  reduce_update_kernel<<<256, 256, 0, stream>>>(partial, cdp, cur, chistT, 1);
  pass_kernel<0, 2><<<1024, 512, 0, stream>>>(out, chistT, ssp, partial, nullptr);
  reduce_update_kernel<<<256, 256, 0, stream>>>(partial, cdp, cur, chistT, 2);
  pass_kernel<0, 3><<<1024, 512, 0, stream>>>(out, chistT, ssp, partial, nullptr);
  reduce_update_kernel<<<256, 256, 0, stream>>>(partial, cdp, cur, chistT, 3);
  pass_kernel<1, 4><<<1024, 512, 0, stream>>>(out, chistT, ssp, nullptr, out);
}

// Round 8
// 879.581 us; speedup vs baseline: 1.0504x; 1.0250x over previous
//
#include <hip/hip_runtime.h>
#include <math.h>

#define NTOK   4096
#define NFEAT  512
#define NDIM   64
#define RROWS  8
#define NBANDS 512   // bands of 8 consecutive rows per batch

typedef float v4f __attribute__((ext_vector_type(4)));

// ---------------- QK projection + RoPE + initial charge ----------------
__global__ __launch_bounds__(256) void qk_kernel(
    const float* __restrict__ feat, const float* __restrict__ cosb,
    const float* __restrict__ sinb, const float* __restrict__ Wq,
    const float* __restrict__ Wk, const float* __restrict__ cw,
    const float* __restrict__ cbp, float* __restrict__ Q, float* __restrict__ K,
    float* __restrict__ cur)
{
  __shared__ __align__(16) float smem[RROWS * NFEAT];  // 16 KB
  const int tid  = threadIdx.x;
  const int row0 = blockIdx.x * RROWS;

  const float4* fb4 = (const float4*)(feat + (size_t)row0 * NFEAT);
  float4* sm4 = (float4*)smem;
#pragma unroll
  for (int i = tid; i < RROWS * NFEAT / 4; i += 256) sm4[i] = fb4[i];
  __syncthreads();

  const int r   = tid >> 5;
  const int c   = tid & 31;
  const int isQ = (c < 16);
  const int d0  = (c & 15) * 4;
  const float* __restrict__ Wp = isQ ? Wq : Wk;
  const float* fr = smem + (r << 9);

  float a0 = 0.f, a1 = 0.f, a2 = 0.f, a3 = 0.f;
  for (int k = 0; k < NFEAT; ++k) {
    float fv = fr[k];
    float4 w = *(const float4*)(Wp + k * NDIM + d0);
    a0 = fmaf(fv, w.x, a0); a1 = fmaf(fv, w.y, a1);
    a2 = fmaf(fv, w.z, a2); a3 = fmaf(fv, w.w, a3);
  }

  float accc = 0.f;
#pragma unroll
  for (int j = 0; j < 16; ++j) accc = fmaf(fr[c + (j << 5)], cw[c + (j << 5)], accc);
#pragma unroll
  for (int o = 16; o > 0; o >>= 1) accc += __shfl_down(accc, o, 64);
  if (c == 0) {
    float cb = cbp[0];
    cur[row0 + r] = 1.f / (1.f + __expf(-(accc + cb)));
  }
  __syncthreads();

  float* sraw = smem;
  {
    float* dst = sraw + r * 132 + (isQ ? 0 : 64) + d0;
    dst[0] = a0; dst[1] = a1; dst[2] = a2; dst[3] = a3;
  }
  __syncthreads();

#pragma unroll
  for (int i = tid; i < RROWS * NDIM; i += 256) {
    int rr = i >> 6, d = i & 63;
    int g = row0 + rr, n = g & (NTOK - 1);
    float cv = cosb[(n << 6) + d], sv = sinb[(n << 6) + d];
    float qv = sraw[rr * 132 + d];
    float qr = (d < 32) ? -sraw[rr * 132 + d + 32] : sraw[rr * 132 + d - 32];
    Q[(size_t)g * NDIM + d] = qv * cv + qr * sv;
    float kv = sraw[rr * 132 + 64 + d];
    float kr = (d < 32) ? -sraw[rr * 132 + 64 + d + 32] : sraw[rr * 132 + 64 + d - 32];
    K[(size_t)g * NDIM + d] = kv * cv + kr * sv;
  }
}

// ---------------- compat = Q K^T / sqrt(64), lower-triangular 128x128 tiles ----------------
__global__ __launch_bounds__(256) void compat_kernel(
    const float* __restrict__ Q, const float* __restrict__ K, float* __restrict__ C)
{
  __shared__ __align__(16) float Qs[32][132];
  __shared__ __align__(16) float Ks[32][132];
  int p = blockIdx.x, b = 0;
  if (p >= 528) { b = 1; p -= 528; }
  int ti = (int)((sqrtf(8.f * p + 1.f) - 1.f) * 0.5f);
  while ((ti + 1) * (ti + 2) / 2 <= p) ++ti;
  while (ti * (ti + 1) / 2 > p) --ti;
  int tj = p - ti * (ti + 1) / 2;

  const int tid = threadIdx.x;
  const int ty = tid >> 4, tx = tid & 15;
  const int i0 = ty * 8, j0 = tx * 8;
  const size_t qbase = ((size_t)b * NTOK + (size_t)ti * 128) * NDIM;
  const size_t kbase = ((size_t)b * NTOK + (size_t)tj * 128) * NDIM;

  float acc[8][8];
#pragma unroll
  for (int ii = 0; ii < 8; ++ii)
#pragma unroll
    for (int jj = 0; jj < 8; ++jj) acc[ii][jj] = 0.f;

  for (int dk = 0; dk < NDIM; dk += 32) {
    __syncthreads();
    for (int i = tid; i < 128 * 32; i += 256) {
      int row = i >> 5, d = i & 31;
      Qs[d][row] = Q[qbase + (size_t)row * NDIM + dk + d];
      Ks[d][row] = K[kbase + (size_t)row * NDIM + dk + d];
    }
    __syncthreads();
#pragma unroll
    for (int d = 0; d < 32; ++d) {
      float4 q0 = *(const float4*)&Qs[d][i0];
      float4 q1 = *(const float4*)&Qs[d][i0 + 4];
      float4 k0 = *(const float4*)&Ks[d][j0];
      float4 k1 = *(const float4*)&Ks[d][j0 + 4];
      float av[8] = {q0.x, q0.y, q0.z, q0.w, q1.x, q1.y, q1.z, q1.w};
      float bv[8] = {k0.x, k0.y, k0.z, k0.w, k1.x, k1.y, k1.z, k1.w};
#pragma unroll
      for (int ii = 0; ii < 8; ++ii)
#pragma unroll
        for (int jj = 0; jj < 8; ++jj)
          acc[ii][jj] = fmaf(av[ii], bv[jj], acc[ii][jj]);
    }
  }
#pragma unroll
  for (int ii = 0; ii < 8; ++ii) {
    size_t grow = (size_t)b * NTOK + (size_t)ti * 128 + i0 + ii;
    float4 w0 = make_float4(acc[ii][0] * 0.125f, acc[ii][1] * 0.125f,
                            acc[ii][2] * 0.125f, acc[ii][3] * 0.125f);
    float4 w1 = make_float4(acc[ii][4] * 0.125f, acc[ii][5] * 0.125f,
                            acc[ii][6] * 0.125f, acc[ii][7] * 0.125f);
    *(float4*)&C[grow * NTOK + (size_t)tj * 128 + j0]     = w0;
    *(float4*)&C[grow * NTOK + (size_t)tj * 128 + j0 + 4] = w1;
  }
}

// ---------------- softmax sweep: asm-blob compat loads + LDS charge history ----------------
// Two latency chains killed together: (1) all compat row loads in ONE asm blob with
// vmcnt(0) drain inside (proven round 6); (2) charge history staged in LDS per block
// (component-major, rp-style permuted slots: 2 lanes/bank, conflict-free) so the
// per-element compute has ZERO global-latency dependence.
template <int MODE, int NSC, int NC>
__device__ __forceinline__ void row_body(
    const int n, const int l,
    const float* __restrict__ rowf, const float* __restrict__ chs,
    const float* h, float* __restrict__ rp, float* __restrict__ outrow)
{
  const int scmax = n >> 8;
  const float* base = rowf + (l << 2);

  v4f cv[NSC];
  if constexpr (NSC == 16) {
    asm volatile(
      "global_load_dwordx4 %0, %16, off\n\t"
      "global_load_dwordx4 %1, %16, off offset:1024\n\t"
      "global_load_dwordx4 %2, %16, off offset:2048\n\t"
      "global_load_dwordx4 %3, %16, off offset:3072\n\t"
      "global_load_dwordx4 %4, %17, off\n\t"
      "global_load_dwordx4 %5, %17, off offset:1024\n\t"
      "global_load_dwordx4 %6, %17, off offset:2048\n\t"
      "global_load_dwordx4 %7, %17, off offset:3072\n\t"
      "global_load_dwordx4 %8, %18, off\n\t"
      "global_load_dwordx4 %9, %18, off offset:1024\n\t"
      "global_load_dwordx4 %10, %18, off offset:2048\n\t"
      "global_load_dwordx4 %11, %18, off offset:3072\n\t"
      "global_load_dwordx4 %12, %19, off\n\t"
      "global_load_dwordx4 %13, %19, off offset:1024\n\t"
      "global_load_dwordx4 %14, %19, off offset:2048\n\t"
      "global_load_dwordx4 %15, %19, off offset:3072\n\t"
      "s_waitcnt vmcnt(0)"
      : "=&v"(cv[0]),  "=&v"(cv[1]),  "=&v"(cv[2]),  "=&v"(cv[3]),
        "=&v"(cv[4]),  "=&v"(cv[5]),  "=&v"(cv[6]),  "=&v"(cv[7]),
        "=&v"(cv[8]),  "=&v"(cv[9]),  "=&v"(cv[10]), "=&v"(cv[11]),
        "=&v"(cv[12]), "=&v"(cv[13]), "=&v"(cv[14]), "=&v"(cv[15])
      : "v"(base), "v"(base + 1024), "v"(base + 2048), "v"(base + 3072)
      : "memory");
  } else {
    asm volatile(
      "global_load_dwordx4 %0, %8, off\n\t"
      "global_load_dwordx4 %1, %8, off offset:1024\n\t"
      "global_load_dwordx4 %2, %8, off offset:2048\n\t"
      "global_load_dwordx4 %3, %8, off offset:3072\n\t"
      "global_load_dwordx4 %4, %9, off\n\t"
      "global_load_dwordx4 %5, %9, off offset:1024\n\t"
      "global_load_dwordx4 %6, %9, off offset:2048\n\t"
      "global_load_dwordx4 %7, %9, off offset:3072\n\t"
      "s_waitcnt vmcnt(0)"
      : "=&v"(cv[0]), "=&v"(cv[1]), "=&v"(cv[2]), "=&v"(cv[3]),
        "=&v"(cv[4]), "=&v"(cv[5]), "=&v"(cv[6]), "=&v"(cv[7])
      : "v"(base), "v"(base + 1024)
      : "memory");
  }

  float vmax = -INFINITY;
#pragma unroll
  for (int sc = 0; sc < NSC; ++sc) {
    const int slot0 = (sc << 8) + l;      // LDS permuted slot base (col = sc*256+4l+i)
    const int cbse  = (sc << 8) + (l << 2);
    float d0 = 0.f, d1 = 0.f, d2 = 0.f, d3 = 0.f;
#pragma unroll
    for (int c = 0; c < NC; ++c) {
      const float* cc = chs + c * NTOK + slot0;
      d0 = fmaf(cc[0],   h[c], d0);
      d1 = fmaf(cc[64],  h[c], d1);
      d2 = fmaf(cc[128], h[c], d2);
      d3 = fmaf(cc[192], h[c], d3);
    }
    float x0 = fmaf(cv[sc].x, d0, cv[sc].x);
    float x1 = fmaf(cv[sc].y, d1, cv[sc].y);
    float x2 = fmaf(cv[sc].z, d2, cv[sc].z);
    float x3 = fmaf(cv[sc].w, d3, cv[sc].w);
    x0 = (cbse + 0 <= n) ? x0 : -INFINITY;  // per-element mask, never a branch
    x1 = (cbse + 1 <= n) ? x1 : -INFINITY;
    x2 = (cbse + 2 <= n) ? x2 : -INFINITY;
    x3 = (cbse + 3 <= n) ? x3 : -INFINITY;
    cv[sc].x = x0; cv[sc].y = x1; cv[sc].z = x2; cv[sc].w = x3;
    vmax = fmaxf(vmax, fmaxf(fmaxf(x0, x1), fmaxf(x2, x3)));
  }
#pragma unroll
  for (int o = 32; o > 0; o >>= 1) vmax = fmaxf(vmax, __shfl_xor(vmax, o, 64));

  float ssum = 0.f;
#pragma unroll
  for (int sc = 0; sc < NSC; ++sc) {
    float v0 = __expf(cv[sc].x - vmax);     // exp(-inf - M) = 0 for masked cols
    float v1 = __expf(cv[sc].y - vmax);
    float v2 = __expf(cv[sc].z - vmax);
    float v3 = __expf(cv[sc].w - vmax);
    cv[sc].x = v0; cv[sc].y = v1; cv[sc].z = v2; cv[sc].w = v3;
    ssum += (v0 + v1) + (v2 + v3);
  }
#pragma unroll
  for (int o = 32; o > 0; o >>= 1) ssum += __shfl_xor(ssum, o, 64);
  const float inv = 1.f / ssum;

  if (MODE == 0) {
#pragma unroll
    for (int sc = 0; sc < NSC; ++sc) {
      if (sc > scmax) continue;             // wave-uniform skip (post-drain, harmless)
      const int slot = (sc << 8) + l;
      atomicAdd(&rp[slot      ], cv[sc].x * inv);
      atomicAdd(&rp[slot +  64], cv[sc].y * inv);
      atomicAdd(&rp[slot + 128], cv[sc].z * inv);
      atomicAdd(&rp[slot + 192], cv[sc].w * inv);
    }
  } else {
    float4* __restrict__ orow = (float4*)outrow;
#pragma unroll
    for (int sc = 0; sc < NSC; ++sc) {
      if (sc > scmax) continue;             // cols beyond (n|255) are memset-0 already
      float4 v;
      v.x = cv[sc].x * inv; v.y = cv[sc].y * inv;
      v.z = cv[sc].z * inv; v.w = cv[sc].w * inv;
      orow[(sc << 6) + l] = v;              // masked cols carry exp(-inf)=0
    }
  }
}

// grid 1024 blocks (2 batches * 512 bands), 512 threads = 8 waves, one row per wave.
// Bands reversed so long-tier bands (rows >= 2048, NSC=16) dispatch first.
template <int MODE, int NC>
__global__ __launch_bounds__(512, 4) void pass_kernel(
    const float* __restrict__ compat, const float* __restrict__ chistT,
    const float* __restrict__ ssp, float* __restrict__ partial,
    float* __restrict__ out)
{
  __shared__ float rp[MODE == 0 ? NTOK : 64];             // 16 KB column partials
  __shared__ float chs[(NC > 0 ? NC : 1) * NTOK];         // NC x 16 KB history slices
  const int tid = threadIdx.x;
  const int b    = blockIdx.x >> 9;
  const int band = (NBANDS - 1) - (blockIdx.x & (NBANDS - 1));
  const int w = __builtin_amdgcn_readfirstlane(tid >> 6);
  const int l = tid & 63;
  const int n = (band << 3) + w;
  const float ss = ssp[0];
  const float* __restrict__ chTg = chistT + (b << 12);    // comp c at +(c<<13)

  if (MODE == 0)
    for (int i = tid; i < NTOK; i += 512) rp[i] = 0.f;
  // stage charge history into LDS, permuted slots, component-major
  const int stlim = (band >= 256) ? NTOK : (NTOK / 2);    // short tier: cols < 2048 only
#pragma unroll
  for (int c = 0; c < NC; ++c)
    for (int i = tid; i < stlim; i += 512) {
      const int slot = (i & ~255) | ((i & 3) << 6) | ((i >> 2) & 63);
      chs[c * NTOK + slot] = chTg[(c << 13) + i];
    }
  __syncthreads();

  float h[NC > 0 ? NC : 1];
  {
    const int slotn = (n & ~255) | ((n & 3) << 6) | ((n >> 2) & 63);
#pragma unroll
    for (int c = 0; c < NC; ++c) h[c] = ss * chs[c * NTOK + slotn];
  }

  const float* rowf = compat + ((size_t)((b << 12) + n) << 12);
  float* outrow = out ? out + ((size_t)((b << 12) + n) << 12) : nullptr;

  if (band >= 256)
    row_body<MODE, 16, NC>(n, l, rowf, chs, h, rp, outrow);
  else
    row_body<MODE, 8, NC>(n, l, rowf, chs, h, rp, outrow);

  if (MODE == 0) {
    __syncthreads();
    float4* __restrict__ pp4 =
        (float4*)(partial + ((size_t)b * NBANDS + band) * (size_t)NTOK);
    const float4* rp4 = (const float4*)rp;
    for (int i = tid; i < NTOK / 4; i += 512) pp4[i] = rp4[i];
  }
}

// ---------------- fold partials -> received, update charge (round-6 proven) ----------------
// Band g covers rows 8g..8g+7 -> touches col m iff g >= m>>3.
__global__ __launch_bounds__(256) void reduce_update_kernel(
    const float* __restrict__ partial, const float* __restrict__ cdp,
    float* __restrict__ cur, float* __restrict__ chistT, int step)
{
  __shared__ float s[8][32];
  const int tid = threadIdx.x;
  const int b = blockIdx.x >> 7;
  const int s0 = (blockIdx.x & 127) << 5;
  const int ml = tid & 31, seg = tid >> 5;
  const int slot = s0 + ml;
  const int m = (slot & ~255) | ((slot & 63) << 2) | ((slot >> 6) & 3);  // inverse perm
  const int bmin = m >> 3;
  float sum = 0.f;
  const float* pb = partial + (size_t)b * NBANDS * NTOK + slot;
  for (int band = bmin + seg; band < NBANDS; band += 8)
    sum += pb[(size_t)band << 12];
  s[seg][ml] = sum;
  __syncthreads();
  if (seg == 0) {
    float r = s[0][ml] + s[1][ml] + s[2][ml] + s[3][ml] +
              s[4][ml] + s[5][ml] + s[6][ml] + s[7][ml];
    float sg = 1.f / (1.f + __expf(-(r - 1.f)));
    float cd = cdp[0];
    int idx = (b << 12) + m;
    float c = cur[idx] * (1.f - cd * sg);
    cur[idx] = c;
    chistT[(step << 13) + idx] = c;
  }
}

extern "C" void kernel_launch(void* const* d_in, const int* in_sizes, int n_in,
                              void* d_out, int out_size, void* d_ws, size_t ws_size,
                              hipStream_t stream) {
  const float* feat = (const float*)d_in[0];
  const float* cosb = (const float*)d_in[1];
  const float* sinb = (const float*)d_in[2];
  // d_in[3] = mask: deterministic tril, handled structurally
  const float* Wq  = (const float*)d_in[4];
  const float* Wk  = (const float*)d_in[5];
  const float* cw  = (const float*)d_in[6];
  const float* cbp = (const float*)d_in[7];
  const float* ssp = (const float*)d_in[8];
  const float* cdp = (const float*)d_in[9];
  float* out = (float*)d_out;

  float* ws      = (float*)d_ws;
  float* Q       = ws;                 // 2*4096*64
  float* K       = ws + 524288;        // 2*4096*64
  float* chistT  = ws + 1048576;       // 4 steps * 2*4096 (component-major history)
  float* cur     = ws + 1081344;       // 2*4096
  float* partial = ws + 1089536;       // 2*512*4096 (permuted column slots)

  // compat lives in d_out (134 MB); final pass overwrites it in place.
  qk_kernel<<<1024, 256, 0, stream>>>(feat, cosb, sinb, Wq, Wk, cw, cbp, Q, K, cur);
  compat_kernel<<<1056, 256, 0, stream>>>(Q, K, out);

  pass_kernel<0, 0><<<1024, 512, 0, stream>>>(out, chistT, ssp, partial, nullptr);
  reduce_update_kernel<<<256, 256, 0, stream>>>(partial, cdp, cur, chistT, 0);
  pass_kernel<0, 1><<<1024, 512, 0, stream>>>(out, chistT, ssp, partial, nullptr);
  reduce_update_kernel<<<256, 256, 0, stream>>>(partial, cdp, cur, chistT, 1);
  pass_kernel<0, 2><<<1024, 512, 0, stream>>>(out, chistT, ssp, partial, nullptr);
  reduce_update_kernel<<<256, 256, 0, stream>>>(partial, cdp, cur, chistT, 2);
  pass_kernel<0, 3><<<1024, 512, 0, stream>>>(out, chistT, ssp, partial, nullptr);
  reduce_update_kernel<<<256, 256, 0, stream>>>(partial, cdp, cur, chistT, 3);
  pass_kernel<1, 4><<<1024, 512, 0, stream>>>(out, chistT, ssp, nullptr, out);
}